// Round 9
// baseline (176.249 us; speedup 1.0000x reference)
//
#include <hip/hip_runtime.h>
#include <stdint.h>
#include <math.h>

#define WAVE 64
#define TOPK 16

// Monotone bijection fp32 -> uint32 (order-preserving).
__device__ __forceinline__ uint32_t f2s(float f) {
    uint32_t u = __float_as_uint(f);
    return u ^ (uint32_t)(((int32_t)u >> 31) | 0x80000000u);
}
__device__ __forceinline__ uint32_t umax32(uint32_t a, uint32_t b) { return a > b ? a : b; }
__device__ __forceinline__ uint32_t umin32(uint32_t a, uint32_t b) { return a < b ? a : b; }

template <int CTRL, int RMASK>
__device__ __forceinline__ uint32_t dppmax(uint32_t m) {
    uint32_t r = (uint32_t)__builtin_amdgcn_update_dpp((int)m, (int)m, CTRL, RMASK, 0xF, false);
    return umax32(m, r);
}

// Wave-wide (64-lane) max, pure VALU (DPP) + one readlane. Returns uniform value.
__device__ __forceinline__ uint32_t wave_umax(uint32_t m) {
    m = dppmax<0x121, 0xF>(m);  // row_ror:1
    m = dppmax<0x122, 0xF>(m);  // row_ror:2
    m = dppmax<0x124, 0xF>(m);  // row_ror:4
    m = dppmax<0x128, 0xF>(m);  // row_ror:8  -> row max everywhere
    m = dppmax<0x142, 0xA>(m);  // row_bcast:15 -> rows 1,3
    m = dppmax<0x143, 0xC>(m);  // row_bcast:31 -> rows 2,3; lane 63 = global
    return (uint32_t)__builtin_amdgcn_readlane((int)m, 63);
}

// global position from (local slot j, lane) -- matches the load layout
template <int VPL>
__device__ __forceinline__ uint32_t gpos(int j, int lane) {
    if constexpr (VPL == 1) return (uint32_t)lane;
    else return (uint32_t)((j >> 2) * (WAVE * 4) + lane * 4 + (j & 3));
}

// Top-16 index selection for one row (R4-validated logic, verbatim).
// qkey = (f2s(v) & ~(P-1)) | global_pos -> unique total order matching stable
// argsort[-k:]. Quantized-boundary ambiguity -> exact lexicographic fallback.
// idx[0..15] are wave-uniform global indices, descending by value.
template <int P>
__device__ __forceinline__ void topk_select(const float* __restrict__ crow,
                                            const int lane,
                                            uint32_t* __restrict__ idx) {
    constexpr int VPL = P / WAVE;
    constexpr uint32_t IMASK = (uint32_t)(P - 1);

    uint32_t k[VPL];
    if constexpr (VPL == 1) {
        k[0] = (f2s(crow[lane]) & ~IMASK) | (uint32_t)lane;
    } else {
#pragma unroll
        for (int c = 0; c < VPL / 4; ++c) {
            float4 f4 = *reinterpret_cast<const float4*>(crow + c * (WAVE * 4) + lane * 4);
            const uint32_t b = (uint32_t)(c * (WAVE * 4) + lane * 4);
            k[c * 4 + 0] = (f2s(f4.x) & ~IMASK) | (b + 0u);
            k[c * 4 + 1] = (f2s(f4.y) & ~IMASK) | (b + 1u);
            k[c * 4 + 2] = (f2s(f4.z) & ~IMASK) | (b + 2u);
            k[c * 4 + 3] = (f2s(f4.w) & ~IMASK) | (b + 3u);
        }
        // bitonic sort, descending, key-only (all indices compile-time)
#pragma unroll
        for (int size = 2; size <= VPL; size <<= 1) {
#pragma unroll
            for (int stride = size >> 1; stride > 0; stride >>= 1) {
#pragma unroll
                for (int i = 0; i < VPL; ++i) {
                    const int j = i ^ stride;
                    if (j > i) {
                        const uint32_t a = k[i], b2 = k[j];
                        const uint32_t hi = umax32(a, b2), lo = umin32(a, b2);
                        if ((i & size) == 0) { k[i] = hi; k[j] = lo; }
                        else                 { k[i] = lo; k[j] = hi; }
                    }
                }
            }
        }
    }

    // 16 rounds: wave max of sorted heads; winner shifts its list.
    uint32_t q16 = 0;
#pragma unroll
    for (int t = 0; t < TOPK; ++t) {
        const uint32_t K = wave_umax(k[0]);
        idx[t] = K & IMASK;
        if (t == TOPK - 1) q16 = K & ~IMASK;
        const bool won = (k[0] == K);   // unique keys -> exactly one lane
#pragma unroll
        for (int j = 0; j < VPL - 1; ++j) k[j] = won ? k[j + 1] : k[j];
        k[VPL - 1] = won ? 0u : k[VPL - 1];
    }
    const uint32_t k17 = wave_umax(k[0]);  // largest remaining

    // Ambiguity: only if the 17th shares the quantized prefix with the 16th.
    if ((k17 & ~IMASK) == q16) {
        // EXACT fallback (rare): lexicographic (value, index) iterative extract.
        uint32_t v[VPL];
        if constexpr (VPL == 1) {
            v[0] = f2s(crow[lane]);
        } else {
#pragma unroll
            for (int c = 0; c < VPL / 4; ++c) {
                float4 f4 = *reinterpret_cast<const float4*>(crow + c * (WAVE * 4) + lane * 4);
                v[c * 4 + 0] = f2s(f4.x);
                v[c * 4 + 1] = f2s(f4.y);
                v[c * 4 + 2] = f2s(f4.z);
                v[c * 4 + 3] = f2s(f4.w);
            }
        }
#pragma unroll
        for (int t = 0; t < TOPK; ++t) {
            uint32_t m = v[0];
            int li = 0;
#pragma unroll
            for (int j = 1; j < VPL; ++j) {
                bool c = v[j] >= m;            // ties -> higher slot (higher index)
                m = c ? v[j] : m;
                li = c ? j : li;
            }
            uint32_t gi = gpos<VPL>(li, lane);
            const uint32_t mygi = gi;
            uint32_t mm = m;
#pragma unroll
            for (int off = 32; off > 0; off >>= 1) {
                uint32_t om = (uint32_t)__shfl_xor((int)mm, off);
                uint32_t og = (uint32_t)__shfl_xor((int)gi, off);
                bool c = (om > mm) || (om == mm && og > gi);
                mm = c ? om : mm;
                gi = c ? og : gi;
            }
            idx[t] = gi;                        // uniform
            const bool won = (mygi == gi) && (m == mm);
#pragma unroll
            for (int j = 0; j < VPL; ++j) {
                if (won && j == li) v[j] = 0u;
            }
        }
    }
}

// Full top-16 weighted mean, returning this lane's (dim=lane) output value.
// Identical op ordering to R4's process_row -> bit-identical numerics.
template <int P>
__device__ __forceinline__ float topk_weighted_value(const float* __restrict__ crow,
                                                     const float* __restrict__ parent,
                                                     const int lane) {
    uint32_t idx[TOPK];
    topk_select<P>(crow, lane, idx);

    float vsel[TOPK];
#pragma unroll
    for (int t = 0; t < TOPK; ++t) vsel[t] = crow[idx[t]];
    const float v0 = vsel[0];
    float ssum = 0.f, acc = 0.f;
#pragma unroll
    for (int t = 0; t < TOPK; ++t) {
        const float w = __expf(vsel[t] - v0);
        ssum += w;
        acc = fmaf(w, parent[idx[t] * 64u + (uint32_t)lane], acc);
    }
    return acc / ssum;
}

// Kernel A: levels 2+1 fused. One wave per conn2 row; the 16 needed e2 rows
// are computed ON DEMAND (redundantly, ~280 ops each) -- no barrier, no e2
// buffer, no extra kernel boundary.
__global__ void level12_kernel(const float* __restrict__ conn2,
                               const float* __restrict__ conn3,
                               const float* __restrict__ root,
                               float* __restrict__ e1,
                               int n1) {
    const int lane = threadIdx.x & (WAVE - 1);
    const int row = blockIdx.x * (blockDim.x >> 6) + (threadIdx.x >> 6);
    if (row >= n1) return;

    const float* __restrict__ crow = conn2 + (long)row * 256;

    uint32_t idx[TOPK];
    topk_select<256>(crow, lane, idx);

    float vsel[TOPK];
#pragma unroll
    for (int t = 0; t < TOPK; ++t) vsel[t] = crow[idx[t]];
    const float v0 = vsel[0];
    float ssum = 0.f, acc = 0.f;
#pragma unroll
    for (int t = 0; t < TOPK; ++t) {
        const float w = __expf(vsel[t] - v0);
        ssum += w;
        // e2[idx[t]][lane] computed on the fly (same numerics as R4's k1)
        const float e2v = topk_weighted_value<64>(conn3 + idx[t] * 64u, root, lane);
        acc = fmaf(w, e2v, acc);
    }
    e1[(long)row * 64 + lane] = acc / ssum;
}

// Kernel B: leaves (unchanged from validated R4 k3).
__global__ void leaf_kernel(const int* __restrict__ ids,
                            const float* __restrict__ conn1,
                            const float* __restrict__ e1,
                            float* __restrict__ out,
                            int batch) {
    const int lane = threadIdx.x & (WAVE - 1);
    const int row = blockIdx.x * (blockDim.x >> 6) + (threadIdx.x >> 6);
    if (row >= batch) return;

    const long src = (long)ids[row];
    out[(long)row * 64 + lane] =
        topk_weighted_value<1024>(conn1 + src * 1024, e1, lane);
}

extern "C" void kernel_launch(void* const* d_in, const int* in_sizes, int n_in,
                              void* d_out, int out_size, void* d_ws, size_t ws_size,
                              hipStream_t stream) {
    const int* ids = (const int*)d_in[0];          // [8192] int32
    const float* conn1 = (const float*)d_in[1];    // [200000, 1024]
    const float* conn2 = (const float*)d_in[2];    // [1024, 256]
    const float* conn3 = (const float*)d_in[3];    // [256, 64]
    const float* root = (const float*)d_in[4];     // [64, 64]
    float* out = (float*)d_out;                    // [8192, 64]

    const int batch = in_sizes[0];                 // 8192
    const int n1 = 1024;

    float* e1 = (float*)d_ws;                      // [1024, 64]

    dim3 blk(256);  // 4 waves/block, one wave per row

    // Levels 2+1 fused (1024 rows)
    level12_kernel<<<dim3(n1 / 4), blk, 0, stream>>>(conn2, conn3, root, e1, n1);

    // Leaves (8192 rows)
    leaf_kernel<<<dim3((batch + 3) / 4), blk, 0, stream>>>(ids, conn1, e1, out, batch);
}

// Round 10
// 49.950 us; speedup vs baseline: 3.5285x; 3.5285x over previous
//
#include <hip/hip_runtime.h>
#include <stdint.h>
#include <math.h>

#define WAVE 64
#define TOPK 16

// ---------- atomics (agent scope, coherence-point, no fences needed) ----------
__device__ __forceinline__ uint32_t aload_u32(const uint32_t* p) {
    return __hip_atomic_load(p, __ATOMIC_RELAXED, __HIP_MEMORY_SCOPE_AGENT);
}
__device__ __forceinline__ float aload_f32(const float* p) {
    return __hip_atomic_load(p, __ATOMIC_RELAXED, __HIP_MEMORY_SCOPE_AGENT);
}
__device__ __forceinline__ void astore_f32(float* p, float v) {
    __hip_atomic_store(p, v, __ATOMIC_RELAXED, __HIP_MEMORY_SCOPE_AGENT);
}
__device__ __forceinline__ void astore_rel_u32(uint32_t* p, uint32_t v) {
    __hip_atomic_store(p, v, __ATOMIC_RELEASE, __HIP_MEMORY_SCOPE_AGENT);
}

// ---------- wave helpers ----------
__device__ __forceinline__ uint32_t f2s(float f) {
    uint32_t u = __float_as_uint(f);
    return u ^ (uint32_t)(((int32_t)u >> 31) | 0x80000000u);
}
__device__ __forceinline__ uint32_t umax32(uint32_t a, uint32_t b) { return a > b ? a : b; }
__device__ __forceinline__ uint32_t umin32(uint32_t a, uint32_t b) { return a < b ? a : b; }

template <int CTRL, int RMASK>
__device__ __forceinline__ uint32_t dppmax(uint32_t m) {
    uint32_t r = (uint32_t)__builtin_amdgcn_update_dpp((int)m, (int)m, CTRL, RMASK, 0xF, false);
    return umax32(m, r);
}
// Wave-wide (64-lane) max, pure VALU (DPP) + one readlane. Returns uniform value.
__device__ __forceinline__ uint32_t wave_umax(uint32_t m) {
    m = dppmax<0x121, 0xF>(m);  // row_ror:1
    m = dppmax<0x122, 0xF>(m);  // row_ror:2
    m = dppmax<0x124, 0xF>(m);  // row_ror:4
    m = dppmax<0x128, 0xF>(m);  // row_ror:8
    m = dppmax<0x142, 0xA>(m);  // row_bcast:15
    m = dppmax<0x143, 0xC>(m);  // row_bcast:31; lane 63 = global max
    return (uint32_t)__builtin_amdgcn_readlane((int)m, 63);
}

template <int VPL>
__device__ __forceinline__ uint32_t gpos(int j, int lane) {
    if constexpr (VPL == 1) return (uint32_t)lane;
    else return (uint32_t)((j >> 2) * (WAVE * 4) + lane * 4 + (j & 3));
}

// ---------- flag waits (no RMW; relaxed polls; producers used release) ----------
template <int NPER>
__device__ __forceinline__ void wait_flags(const uint32_t* flags, int lane) {
    int spins = 0;
    for (;;) {
        uint32_t ok = 1u;
#pragma unroll
        for (int j = 0; j < NPER; ++j)
            ok &= aload_u32(flags + lane + j * WAVE);
        if (__all(ok == 1u)) return;
        __builtin_amdgcn_s_sleep(16);
        if (++spins > (1 << 20)) return;  // ~0.4s safety: fail visibly, not hang
    }
}
__device__ __forceinline__ void wait_flag1(const uint32_t* f) {
    int spins = 0;
    while (aload_u32(f) != 1u) {
        __builtin_amdgcn_s_sleep(16);
        if (++spins > (1 << 20)) return;
    }
}

// ---------- R4-validated top-16 selection (verbatim numerics) ----------
template <int P>
__device__ __forceinline__ void topk_select(const float* __restrict__ crow,
                                            const int lane,
                                            uint32_t* __restrict__ idx) {
    constexpr int VPL = P / WAVE;
    constexpr uint32_t IMASK = (uint32_t)(P - 1);

    uint32_t k[VPL];
    if constexpr (VPL == 1) {
        k[0] = (f2s(crow[lane]) & ~IMASK) | (uint32_t)lane;
    } else {
#pragma unroll
        for (int c = 0; c < VPL / 4; ++c) {
            float4 f4 = *reinterpret_cast<const float4*>(crow + c * (WAVE * 4) + lane * 4);
            const uint32_t b = (uint32_t)(c * (WAVE * 4) + lane * 4);
            k[c * 4 + 0] = (f2s(f4.x) & ~IMASK) | (b + 0u);
            k[c * 4 + 1] = (f2s(f4.y) & ~IMASK) | (b + 1u);
            k[c * 4 + 2] = (f2s(f4.z) & ~IMASK) | (b + 2u);
            k[c * 4 + 3] = (f2s(f4.w) & ~IMASK) | (b + 3u);
        }
#pragma unroll
        for (int size = 2; size <= VPL; size <<= 1) {
#pragma unroll
            for (int stride = size >> 1; stride > 0; stride >>= 1) {
#pragma unroll
                for (int i = 0; i < VPL; ++i) {
                    const int j = i ^ stride;
                    if (j > i) {
                        const uint32_t a = k[i], b2 = k[j];
                        const uint32_t hi = umax32(a, b2), lo = umin32(a, b2);
                        if ((i & size) == 0) { k[i] = hi; k[j] = lo; }
                        else                 { k[i] = lo; k[j] = hi; }
                    }
                }
            }
        }
    }

    uint32_t q16 = 0;
#pragma unroll
    for (int t = 0; t < TOPK; ++t) {
        const uint32_t K = wave_umax(k[0]);
        idx[t] = K & IMASK;
        if (t == TOPK - 1) q16 = K & ~IMASK;
        const bool won = (k[0] == K);
#pragma unroll
        for (int j = 0; j < VPL - 1; ++j) k[j] = won ? k[j + 1] : k[j];
        k[VPL - 1] = won ? 0u : k[VPL - 1];
    }
    const uint32_t k17 = wave_umax(k[0]);

    if ((k17 & ~IMASK) == q16) {
        // EXACT fallback (rare): lexicographic (value, index) iterative extract.
        uint32_t v[VPL];
        if constexpr (VPL == 1) {
            v[0] = f2s(crow[lane]);
        } else {
#pragma unroll
            for (int c = 0; c < VPL / 4; ++c) {
                float4 f4 = *reinterpret_cast<const float4*>(crow + c * (WAVE * 4) + lane * 4);
                v[c * 4 + 0] = f2s(f4.x);
                v[c * 4 + 1] = f2s(f4.y);
                v[c * 4 + 2] = f2s(f4.z);
                v[c * 4 + 3] = f2s(f4.w);
            }
        }
#pragma unroll
        for (int t = 0; t < TOPK; ++t) {
            uint32_t m = v[0];
            int li = 0;
#pragma unroll
            for (int j = 1; j < VPL; ++j) {
                bool c = v[j] >= m;
                m = c ? v[j] : m;
                li = c ? j : li;
            }
            uint32_t gi = gpos<VPL>(li, lane);
            const uint32_t mygi = gi;
            uint32_t mm = m;
#pragma unroll
            for (int off = 32; off > 0; off >>= 1) {
                uint32_t om = (uint32_t)__shfl_xor((int)mm, off);
                uint32_t og = (uint32_t)__shfl_xor((int)gi, off);
                bool c = (om > mm) || (om == mm && og > gi);
                mm = c ? om : mm;
                gi = c ? og : gi;
            }
            idx[t] = gi;
            const bool won = (mygi == gi) && (m == mm);
#pragma unroll
            for (int j = 0; j < VPL; ++j) {
                if (won && j == li) v[j] = 0u;
            }
        }
    }
}

// Full weighted value for this lane; AT -> parent read via agent atomic loads.
template <int P, bool AT>
__device__ __forceinline__ float topk_wval(const float* __restrict__ crow,
                                           const float* __restrict__ parent,
                                           const int lane) {
    uint32_t idx[TOPK];
    topk_select<P>(crow, lane, idx);
    float vsel[TOPK];
#pragma unroll
    for (int t = 0; t < TOPK; ++t) vsel[t] = crow[idx[t]];
    const float v0 = vsel[0];
    float ssum = 0.f, acc = 0.f;
#pragma unroll
    for (int t = 0; t < TOPK; ++t) {
        const float w = __expf(vsel[t] - v0);
        ssum += w;
        const float pv = AT ? aload_f32(parent + idx[t] * 64u + (uint32_t)lane)
                            : parent[idx[t] * 64u + (uint32_t)lane];
        acc = fmaf(w, pv, acc);
    }
    return acc / ssum;
}

// ---------- single fused kernel: producer/consumer flags, no barrier ----------
#define K3_BLOCKS 2048

__global__ void __launch_bounds__(256, 4)
fused_all(const int* __restrict__ ids,
          const float* __restrict__ conn1,
          const float* __restrict__ conn2,
          const float* __restrict__ conn3,
          const float* __restrict__ root,
          uint32_t* __restrict__ fe2,     // [256] flags
          uint32_t* __restrict__ fe1,     // [1024] flags
          uint32_t* __restrict__ all_e1,  // [1] aggregated flag
          float* __restrict__ e2,         // [256*64]
          float* __restrict__ e1,         // [1024*64]
          float* __restrict__ out,
          int batch) {
    const int lane = threadIdx.x & (WAVE - 1);
    const int wib = threadIdx.x >> 6;
    const int bid = blockIdx.x;

    if (bid < 256) {
        // ---- producer block ----
        // Wave 0: e2 row `bid` FIRST (cross-block critical path).
        if (wib == 0) {
            const float v = topk_wval<64, false>(conn3 + bid * 64, root, lane);
            astore_f32(&e2[bid * 64 + lane], v);
            asm volatile("s_waitcnt vmcnt(0)" ::: "memory");  // drain wave's stores
            if (lane == 0) astore_rel_u32(&fe2[bid], 1u);
        }
        // All waves: conn2 selection (independent of e2).
        const int row = bid * 4 + wib;
        const float* __restrict__ crow = conn2 + (long)row * 256;
        uint32_t idx[TOPK];
        topk_select<256>(crow, lane, idx);
        float vsel[TOPK];
#pragma unroll
        for (int t = 0; t < TOPK; ++t) vsel[t] = crow[idx[t]];

        wait_flags<4>(fe2, lane);  // 256 e2 flags; set long before we get here

        const float v0 = vsel[0];
        float ssum = 0.f, acc = 0.f;
#pragma unroll
        for (int t = 0; t < TOPK; ++t) {
            const float w = __expf(vsel[t] - v0);
            ssum += w;
            acc = fmaf(w, aload_f32(&e2[idx[t] * 64u + (uint32_t)lane]), acc);
        }
        astore_f32(&e1[row * 64 + lane], acc / ssum);
        asm volatile("s_waitcnt vmcnt(0)" ::: "memory");
        if (lane == 0) astore_rel_u32(&fe1[row], 1u);

        // Block 0 wave 0: aggregate 1024 e1 flags -> one flag for k3 waves.
        if (bid == 0 && wib == 0) {
            wait_flags<16>(fe1, lane);
            if (lane == 0) astore_rel_u32(all_e1, 1u);
        }
    } else {
        // ---- leaf (k3) block ----
        bool ready = false;
        for (int r = (bid - 256) * 4 + wib; r < batch; r += K3_BLOCKS * 4) {
            const float* __restrict__ crow = conn1 + (long)ids[r] * 1024;
            uint32_t idx[TOPK];
            topk_select<1024>(crow, lane, idx);
            float vsel[TOPK];
#pragma unroll
            for (int t = 0; t < TOPK; ++t) vsel[t] = crow[idx[t]];

            if (!ready) { wait_flag1(all_e1); ready = true; }  // ~0 stall: set by now

            const float v0 = vsel[0];
            float ssum = 0.f, acc = 0.f;
#pragma unroll
            for (int t = 0; t < TOPK; ++t) {
                const float w = __expf(vsel[t] - v0);
                ssum += w;
                acc = fmaf(w, aload_f32(&e1[idx[t] * 64u + (uint32_t)lane]), acc);
            }
            out[(long)r * 64 + lane] = acc / ssum;
        }
    }
}

extern "C" void kernel_launch(void* const* d_in, const int* in_sizes, int n_in,
                              void* d_out, int out_size, void* d_ws, size_t ws_size,
                              hipStream_t stream) {
    const int* ids = (const int*)d_in[0];          // [8192] int32
    const float* conn1 = (const float*)d_in[1];    // [200000, 1024]
    const float* conn2 = (const float*)d_in[2];    // [1024, 256]
    const float* conn3 = (const float*)d_in[3];    // [256, 64]
    const float* root = (const float*)d_in[4];     // [64, 64]
    float* out = (float*)d_out;                    // [8192, 64]

    int batch = in_sizes[0];                       // 8192

    uint32_t* fe2 = (uint32_t*)d_ws;               // [256]
    uint32_t* fe1 = fe2 + 256;                     // [1024]
    uint32_t* all_e1 = fe2 + 1280;                 // [1]
    float* e2 = (float*)((char*)d_ws + 8192);      // [256*64]
    float* e1 = e2 + 256 * 64;                     // [1024*64]

    // Zero the flag region (graph-legal async memset, 8 KB).
    hipMemsetAsync(d_ws, 0, 8192, stream);

    fused_all<<<dim3(256 + K3_BLOCKS), dim3(256), 0, stream>>>(
        ids, conn1, conn2, conn3, root, fe2, fe1, all_e1, e2, e1, out, batch);
}

// Round 11
// 32.815 us; speedup vs baseline: 5.3711x; 1.5222x over previous
//
#include <hip/hip_runtime.h>
#include <stdint.h>
#include <math.h>

#define WAVE 64
#define TOPK 16

// Monotone bijection fp32 -> uint32 (order-preserving).
__device__ __forceinline__ uint32_t f2s(float f) {
    uint32_t u = __float_as_uint(f);
    return u ^ (uint32_t)(((int32_t)u >> 31) | 0x80000000u);
}
__device__ __forceinline__ uint32_t umax32(uint32_t a, uint32_t b) { return a > b ? a : b; }
__device__ __forceinline__ uint32_t umin32(uint32_t a, uint32_t b) { return a < b ? a : b; }

template <int CTRL, int RMASK>
__device__ __forceinline__ uint32_t dppmax(uint32_t m) {
    uint32_t r = (uint32_t)__builtin_amdgcn_update_dpp((int)m, (int)m, CTRL, RMASK, 0xF, false);
    return umax32(m, r);
}
// Wave-wide (64-lane) max, pure VALU (DPP) + one readlane. Returns uniform value.
__device__ __forceinline__ uint32_t wave_umax(uint32_t m) {
    m = dppmax<0x121, 0xF>(m);  // row_ror:1
    m = dppmax<0x122, 0xF>(m);  // row_ror:2
    m = dppmax<0x124, 0xF>(m);  // row_ror:4
    m = dppmax<0x128, 0xF>(m);  // row_ror:8  -> row max everywhere
    m = dppmax<0x142, 0xA>(m);  // row_bcast:15 -> rows 1,3
    m = dppmax<0x143, 0xC>(m);  // row_bcast:31 -> rows 2,3; lane 63 = global
    return (uint32_t)__builtin_amdgcn_readlane((int)m, 63);
}

template <int VPL>
__device__ __forceinline__ uint32_t gpos(int j, int lane) {
    if constexpr (VPL == 1) return (uint32_t)lane;
    else return (uint32_t)((j >> 2) * (WAVE * 4) + lane * 4 + (j & 3));
}

#define CE_(x, y) { const uint32_t h_ = umax32(x, y), l_ = umin32(x, y); (x) = h_; (y) = l_; }

// ---------- generic top-16 selection (R4-verbatim) for P=64/256 ----------
template <int P>
__device__ __forceinline__ void topk_select(const float* __restrict__ crow,
                                            const int lane,
                                            uint32_t* __restrict__ idx) {
    constexpr int VPL = P / WAVE;
    constexpr uint32_t IMASK = (uint32_t)(P - 1);

    uint32_t k[VPL];
    if constexpr (VPL == 1) {
        k[0] = (f2s(crow[lane]) & ~IMASK) | (uint32_t)lane;
    } else {
#pragma unroll
        for (int c = 0; c < VPL / 4; ++c) {
            float4 f4 = *reinterpret_cast<const float4*>(crow + c * (WAVE * 4) + lane * 4);
            const uint32_t b = (uint32_t)(c * (WAVE * 4) + lane * 4);
            k[c * 4 + 0] = (f2s(f4.x) & ~IMASK) | (b + 0u);
            k[c * 4 + 1] = (f2s(f4.y) & ~IMASK) | (b + 1u);
            k[c * 4 + 2] = (f2s(f4.z) & ~IMASK) | (b + 2u);
            k[c * 4 + 3] = (f2s(f4.w) & ~IMASK) | (b + 3u);
        }
#pragma unroll
        for (int size = 2; size <= VPL; size <<= 1) {
#pragma unroll
            for (int stride = size >> 1; stride > 0; stride >>= 1) {
#pragma unroll
                for (int i = 0; i < VPL; ++i) {
                    const int j = i ^ stride;
                    if (j > i) {
                        if ((i & size) == 0) { CE_(k[i], k[j]); }
                        else                 { CE_(k[j], k[i]); }
                    }
                }
            }
        }
    }

    uint32_t q16 = 0;
#pragma unroll
    for (int t = 0; t < TOPK; ++t) {
        const uint32_t K = wave_umax(k[0]);
        idx[t] = K & IMASK;
        if (t == TOPK - 1) q16 = K & ~IMASK;
        const bool won = (k[0] == K);
#pragma unroll
        for (int j = 0; j < VPL - 1; ++j) k[j] = won ? k[j + 1] : k[j];
        k[VPL - 1] = won ? 0u : k[VPL - 1];
    }
    const uint32_t k17 = wave_umax(k[0]);

    if ((k17 & ~IMASK) == q16) {
        // EXACT fallback (rare): lexicographic (value, index) iterative extract.
        uint32_t v[VPL];
        if constexpr (VPL == 1) {
            v[0] = f2s(crow[lane]);
        } else {
#pragma unroll
            for (int c = 0; c < VPL / 4; ++c) {
                float4 f4 = *reinterpret_cast<const float4*>(crow + c * (WAVE * 4) + lane * 4);
                v[c * 4 + 0] = f2s(f4.x);
                v[c * 4 + 1] = f2s(f4.y);
                v[c * 4 + 2] = f2s(f4.z);
                v[c * 4 + 3] = f2s(f4.w);
            }
        }
#pragma unroll
        for (int t = 0; t < TOPK; ++t) {
            uint32_t m = v[0];
            int li = 0;
#pragma unroll
            for (int j = 1; j < VPL; ++j) {
                bool c = v[j] >= m;
                m = c ? v[j] : m;
                li = c ? j : li;
            }
            uint32_t gi = gpos<VPL>(li, lane);
            const uint32_t mygi = gi;
            uint32_t mm = m;
#pragma unroll
            for (int off = 32; off > 0; off >>= 1) {
                uint32_t om = (uint32_t)__shfl_xor((int)mm, off);
                uint32_t og = (uint32_t)__shfl_xor((int)gi, off);
                bool c = (om > mm) || (om == mm && og > gi);
                mm = c ? om : mm;
                gi = c ? og : gi;
            }
            idx[t] = gi;
            const bool won = (mygi == gi) && (m == mm);
#pragma unroll
            for (int j = 0; j < VPL; ++j) {
                if (won && j == li) v[j] = 0u;
            }
        }
    }
}

// ---------- specialized P=1024: top-4 sorted head + 12-entry reserve ----------
// Invariant: t[] sorted desc, every reserve element <= true 4th-largest, so
// t[0] is always the lane's current max (0-sentinel = refill from reserve).
// Winner sequence (and thus selected set) identical to the full-sort version.
__device__ __forceinline__ void topk_select_1024(const float* __restrict__ crow,
                                                 const int lane,
                                                 uint32_t* __restrict__ idx) {
    constexpr uint32_t IMASK = 1023u;

    uint32_t k[16];
#pragma unroll
    for (int c = 0; c < 4; ++c) {
        float4 f4 = *reinterpret_cast<const float4*>(crow + c * (WAVE * 4) + lane * 4);
        const uint32_t b = (uint32_t)(c * (WAVE * 4) + lane * 4);
        k[c * 4 + 0] = (f2s(f4.x) & ~IMASK) | (b + 0u);
        k[c * 4 + 1] = (f2s(f4.y) & ~IMASK) | (b + 1u);
        k[c * 4 + 2] = (f2s(f4.z) & ~IMASK) | (b + 2u);
        k[c * 4 + 3] = (f2s(f4.w) & ~IMASK) | (b + 3u);
    }
    // sort each quad desc (5 CE each)
#pragma unroll
    for (int c = 0; c < 4; ++c) {
        CE_(k[4 * c + 0], k[4 * c + 1]); CE_(k[4 * c + 2], k[4 * c + 3]);
        CE_(k[4 * c + 0], k[4 * c + 2]); CE_(k[4 * c + 1], k[4 * c + 3]);
        CE_(k[4 * c + 1], k[4 * c + 2]);
    }
    uint32_t h[4], g[4], t[4], r[12];
    // merge quads 0,1 -> h (top4 sorted), r[0..3] (losers, unsorted)
#pragma unroll
    for (int i = 0; i < 4; ++i) { h[i] = umax32(k[i], k[7 - i]); r[i] = umin32(k[i], k[7 - i]); }
    CE_(h[0], h[2]); CE_(h[1], h[3]); CE_(h[0], h[1]); CE_(h[2], h[3]);
    // merge quads 2,3 -> g, r[4..7]
#pragma unroll
    for (int i = 0; i < 4; ++i) { g[i] = umax32(k[8 + i], k[15 - i]); r[4 + i] = umin32(k[8 + i], k[15 - i]); }
    CE_(g[0], g[2]); CE_(g[1], g[3]); CE_(g[0], g[1]); CE_(g[2], g[3]);
    // final merge -> t (top4 of 16, sorted), r[8..11]
#pragma unroll
    for (int i = 0; i < 4; ++i) { t[i] = umax32(h[i], g[3 - i]); r[8 + i] = umin32(h[i], g[3 - i]); }
    CE_(t[0], t[2]); CE_(t[1], t[3]); CE_(t[0], t[1]); CE_(t[2], t[3]);

    uint32_t q16 = 0;
#pragma unroll
    for (int tt = 0; tt < TOPK; ++tt) {
        // lazy refill (wave-uniform rare branch): head exhausted -> pull reserve max
        if (__any(t[0] == 0u)) {
            const bool need = (t[0] == 0u);
            uint32_t rm = r[0];
#pragma unroll
            for (int j = 1; j < 12; ++j) rm = umax32(rm, r[j]);
#pragma unroll
            for (int j = 0; j < 12; ++j) r[j] = (need && r[j] == rm) ? 0u : r[j];
            t[0] = need ? rm : t[0];
        }
        const uint32_t K = wave_umax(t[0]);
        idx[tt] = K & IMASK;
        if (tt == TOPK - 1) q16 = K & ~IMASK;
        const bool won = (t[0] == K);   // unique keys -> exactly one lane
        t[0] = won ? t[1] : t[0];
        t[1] = won ? t[2] : t[1];
        t[2] = won ? t[3] : t[2];
        t[3] = won ? 0u : t[3];
    }
    // refill once more so heads include reserves, then 17th-largest
    if (__any(t[0] == 0u)) {
        const bool need = (t[0] == 0u);
        uint32_t rm = r[0];
#pragma unroll
        for (int j = 1; j < 12; ++j) rm = umax32(rm, r[j]);
        t[0] = need ? rm : t[0];
    }
    const uint32_t k17 = wave_umax(t[0]);

    if ((k17 & ~IMASK) == q16) {
        // EXACT fallback (rare): lexicographic (value, index) iterative extract.
        uint32_t v[16];
#pragma unroll
        for (int c = 0; c < 4; ++c) {
            float4 f4 = *reinterpret_cast<const float4*>(crow + c * (WAVE * 4) + lane * 4);
            v[c * 4 + 0] = f2s(f4.x);
            v[c * 4 + 1] = f2s(f4.y);
            v[c * 4 + 2] = f2s(f4.z);
            v[c * 4 + 3] = f2s(f4.w);
        }
#pragma unroll
        for (int tt = 0; tt < TOPK; ++tt) {
            uint32_t m = v[0];
            int li = 0;
#pragma unroll
            for (int j = 1; j < 16; ++j) {
                bool c = v[j] >= m;
                m = c ? v[j] : m;
                li = c ? j : li;
            }
            uint32_t gi = gpos<16>(li, lane);
            const uint32_t mygi = gi;
            uint32_t mm = m;
#pragma unroll
            for (int off = 32; off > 0; off >>= 1) {
                uint32_t om = (uint32_t)__shfl_xor((int)mm, off);
                uint32_t og = (uint32_t)__shfl_xor((int)gi, off);
                bool c = (om > mm) || (om == mm && og > gi);
                mm = c ? om : mm;
                gi = c ? og : gi;
            }
            idx[tt] = gi;
            const bool won = (mygi == gi) && (m == mm);
#pragma unroll
            for (int j = 0; j < 16; ++j) {
                if (won && j == li) v[j] = 0u;
            }
        }
    }
}

// ---------- per-row kernel (epilogue R4-verbatim) ----------
template <int P>
__global__ void topk_wm_kernel(const float* __restrict__ conn,
                               const int* __restrict__ rowsel,
                               const float* __restrict__ parent,
                               float* __restrict__ out,
                               int n) {
    const int lane = threadIdx.x & (WAVE - 1);
    const int row = blockIdx.x * (blockDim.x >> 6) + (threadIdx.x >> 6);
    if (row >= n) return;

    const long src_row = rowsel ? (long)rowsel[row] : (long)row;
    const float* __restrict__ crow = conn + src_row * (long)P;

    uint32_t idx[TOPK];
    if constexpr (P == 1024) topk_select_1024(crow, lane, idx);
    else                     topk_select<P>(crow, lane, idx);

    float vsel[TOPK];
#pragma unroll
    for (int t = 0; t < TOPK; ++t) vsel[t] = crow[idx[t]];
    const float v0 = vsel[0];
    float ssum = 0.f, acc = 0.f;
#pragma unroll
    for (int t = 0; t < TOPK; ++t) {
        const float w = __expf(vsel[t] - v0);
        ssum += w;
        acc = fmaf(w, parent[idx[t] * 64u + (uint32_t)lane], acc);
    }
    out[(long)row * 64 + lane] = acc / ssum;
}

extern "C" void kernel_launch(void* const* d_in, const int* in_sizes, int n_in,
                              void* d_out, int out_size, void* d_ws, size_t ws_size,
                              hipStream_t stream) {
    const int* ids = (const int*)d_in[0];          // [8192] int32
    const float* conn1 = (const float*)d_in[1];    // [200000, 1024]
    const float* conn2 = (const float*)d_in[2];    // [1024, 256]
    const float* conn3 = (const float*)d_in[3];    // [256, 64]
    const float* root = (const float*)d_in[4];     // [64, 64]
    float* out = (float*)d_out;                    // [8192, 64]

    const int batch = in_sizes[0];                 // 8192
    const int n1 = 1024, n2 = 256;

    float* e2 = (float*)d_ws;                      // [256, 64]
    float* e1 = e2 + (size_t)n2 * 64;              // [1024, 64]

    // Level 2: 256 rows, one wave per block (max CU spread for latency)
    topk_wm_kernel<64><<<dim3(n2), dim3(64), 0, stream>>>(conn3, nullptr, root, e2, n2);

    // Level 1: 1024 rows, 4 waves/block
    topk_wm_kernel<256><<<dim3(n1 / 4), dim3(256), 0, stream>>>(conn2, nullptr, e2, e1, n1);

    // Leaves: 8192 rows, 4 waves/block
    topk_wm_kernel<1024><<<dim3(batch / 4), dim3(256), 0, stream>>>(conn1, ids, e1, out, batch);
}